// Round 1
// baseline (818.054 us; speedup 1.0000x reference)
//
#include <hip/hip_runtime.h>
#include <math.h>

#define T_STEPS 512
#define NB      16
#define D_IN    512
#define CG      4096
#define CO      5120
#define NSTATES 1024
#define LMAX    252
#define NEGF    (-1e30f)
#define SCORES_SZ 41943040LL   // NB * T_STEPS * CO

__device__ __forceinline__ float tanh5(float x) {
    x = fminf(fmaxf(x, -15.f), 15.f);
    float e = __expf(2.f * x);
    return 5.f * (e - 1.f) / (e + 1.f);
}

// ---------------- GEMM + tanh*5 + blank interleave, writes both score copies ----------------
#define BM 128
#define BN 128
#define BK 16

__global__ __launch_bounds__(256) void crf_gemm_kernel(
    const float* __restrict__ A,      // hs_pad as (8192, 512), row m = n*512 + t
    const float* __restrict__ W,      // (4096, 512)
    const float* __restrict__ bias,   // (4096)
    float* __restrict__ out)          // full d_out
{
    __shared__ float As[BK][BM + 4];
    __shared__ float Bs[BK][BN + 4];
    const int tid = threadIdx.x;
    const int tx = tid & 15, ty = tid >> 4;
    const int m0 = blockIdx.y * BM;
    const int n0 = blockIdx.x * BN;

    float acc[8][8];
    #pragma unroll
    for (int i = 0; i < 8; ++i)
        #pragma unroll
        for (int j = 0; j < 8; ++j) acc[i][j] = 0.f;

    const int lrow = tid >> 2;          // 0..63
    const int lk   = (tid & 3) << 2;    // 0,4,8,12

    for (int k0 = 0; k0 < D_IN; k0 += BK) {
        #pragma unroll
        for (int h = 0; h < 2; ++h) {
            const int row = lrow + h * 64;
            float4 av = *(const float4*)(A + (size_t)(m0 + row) * D_IN + k0 + lk);
            As[lk + 0][row] = av.x; As[lk + 1][row] = av.y;
            As[lk + 2][row] = av.z; As[lk + 3][row] = av.w;
            float4 wv = *(const float4*)(W + (size_t)(n0 + row) * D_IN + k0 + lk);
            Bs[lk + 0][row] = wv.x; Bs[lk + 1][row] = wv.y;
            Bs[lk + 2][row] = wv.z; Bs[lk + 3][row] = wv.w;
        }
        __syncthreads();
        #pragma unroll
        for (int kk = 0; kk < BK; ++kk) {
            float a[8], bb[8];
            *(float4*)&a[0]  = *(const float4*)&As[kk][ty * 8];
            *(float4*)&a[4]  = *(const float4*)&As[kk][ty * 8 + 4];
            *(float4*)&bb[0] = *(const float4*)&Bs[kk][tx * 8];
            *(float4*)&bb[4] = *(const float4*)&Bs[kk][tx * 8 + 4];
            #pragma unroll
            for (int i = 0; i < 8; ++i)
                #pragma unroll
                for (int j = 0; j < 8; ++j)
                    acc[i][j] = fmaf(a[i], bb[j], acc[i][j]);
        }
        __syncthreads();
    }

    float bv[8];
    #pragma unroll
    for (int j = 0; j < 8; ++j) bv[j] = bias[n0 + tx * 8 + j];

    #pragma unroll
    for (int i = 0; i < 8; ++i) {
        const int m = m0 + ty * 8 + i;
        float* r1 = out + 16 + (size_t)m * CO;
        float* r2 = r1 + SCORES_SZ;
        #pragma unroll
        for (int jg = 0; jg < 2; ++jg) {
            const int c0 = n0 + tx * 8 + jg * 4;
            const int ch = (c0 >> 2) * 5;
            r1[ch] = 2.0f; r2[ch] = 2.0f;
            #pragma unroll
            for (int j = 0; j < 4; ++j) {
                float v = tanh5(acc[i][jg * 4 + j] + bv[jg * 4 + j]);
                r1[ch + 1 + j] = v;
                r2[ch + 1 + j] = v;
            }
        }
    }
}

// ---------------- CRF full-forward (blocks 0..15) + CTC unnorm forward (blocks 16..31) ----------------
__global__ __launch_bounds__(1024) void crf_fwd_kernel(
    const float* __restrict__ scores,   // (NB*T_STEPS, CO), row m = n*512 + t
    const int* __restrict__ ys_pad,     // (NB, 256)
    const int* __restrict__ ys_lens,    // (NB)
    float* __restrict__ ws)             // ws[0..15]=logZ, ws[16..31]=un
{
    const int blk = blockIdx.x;
    if (blk < NB) {
        // ---- CRF logZ over 1024 states ----
        const int n = blk;
        const int s = threadIdx.x;
        __shared__ float buf[2][NSTATES];
        __shared__ float red[NSTATES];
        float alpha = 0.f;
        buf[0][s] = 0.f;
        __syncthreads();
        int cur = 0;
        const int j0 = s >> 2;
        const float* row = scores + (size_t)(n * T_STEPS) * CO + 5 * s + 1;
        float m1 = row[0], m2 = row[1], m3 = row[2], m4 = row[3];
        for (int t = 0; t < T_STEPS; ++t) {
            const float* nrow = row + CO;
            float p1 = 0.f, p2 = 0.f, p3 = 0.f, p4 = 0.f;
            if (t + 1 < T_STEPS) { p1 = nrow[0]; p2 = nrow[1]; p3 = nrow[2]; p4 = nrow[3]; }
            float a0 = alpha + 2.0f;
            float a1 = buf[cur][j0]       + m1;
            float a2 = buf[cur][j0 + 256] + m2;
            float a3 = buf[cur][j0 + 512] + m3;
            float a4 = buf[cur][j0 + 768] + m4;
            float mx = fmaxf(fmaxf(fmaxf(a0, a1), fmaxf(a2, a3)), a4);
            float sum = __expf(a0 - mx) + __expf(a1 - mx) + __expf(a2 - mx)
                      + __expf(a3 - mx) + __expf(a4 - mx);
            alpha = mx + __logf(sum);
            buf[cur ^ 1][s] = alpha;
            __syncthreads();
            cur ^= 1;
            m1 = p1; m2 = p2; m3 = p3; m4 = p4;
            row = nrow;
        }
        // logsumexp reduce over 1024 states
        red[s] = alpha;
        __syncthreads();
        for (int off = 512; off > 0; off >>= 1) {
            if (s < off) red[s] = fmaxf(red[s], red[s + off]);
            __syncthreads();
        }
        const float gmax = red[0];
        __syncthreads();
        red[s] = __expf(alpha - gmax);
        __syncthreads();
        for (int off = 512; off > 0; off >>= 1) {
            if (s < off) red[s] += red[s + off];
            __syncthreads();
        }
        if (s == 0) ws[n] = gmax + __logf(red[0]);
    } else {
        // ---- CTC forward on unnormalized scores; stay score is constant 2.0 (blank channel) ----
        const int n = blk - NB;
        const int i = threadIdx.x;
        __shared__ float abuf[2][LMAX];
        __shared__ int tcl[256];
        if (i < 256) tcl[i] = max(ys_pad[n * 256 + i] - 1, 0);
        __syncthreads();
        int mch = -1;
        if (i >= 1 && i < LMAX) {
            const int code = tcl[i] * 256 + tcl[i + 1] * 64 + tcl[i + 2] * 16
                           + tcl[i + 3] * 4 + tcl[i + 4];
            mch = code * 5 + tcl[i - 1] + 1;
        }
        float alpha = (i == 0) ? 0.f : NEGF;
        if (i < LMAX) abuf[0][i] = alpha;
        __syncthreads();
        int cur = 0;
        const float* row = scores + (size_t)(n * T_STEPS) * CO;
        float g = (mch >= 0) ? row[mch] : 0.f;
        for (int t = 0; t < T_STEPS; ++t) {
            const float* nrow = row + CO;
            float gn = 0.f;
            if (t + 1 < T_STEPS && mch >= 0) gn = nrow[mch];
            if (i < LMAX) {
                const float a_stay = alpha + 2.0f;
                const float prev = (i > 0) ? abuf[cur][i - 1] : NEGF;
                const float a_mv = (i > 0) ? (prev + g) : NEGF;
                const float mx = fmaxf(a_stay, a_mv);
                const float mn = fminf(a_stay, a_mv);
                alpha = mx + __logf(1.f + __expf(mn - mx));
                abuf[cur ^ 1][i] = alpha;
            }
            __syncthreads();
            cur ^= 1;
            g = gn;
            row = nrow;
        }
        if (i == ys_lens[n] - 5) ws[NB + n] = alpha;   // alphaT[lens-1], lens = ys_lens - 4
    }
}

// ---------------- loss = -((un - logZ) / ys_lens) ----------------
__global__ void crf_loss_kernel(const float* __restrict__ ws,
                                const int* __restrict__ ys_lens,
                                float* __restrict__ out)
{
    const int n = threadIdx.x;
    if (n < NB) {
        const float logz = ws[NB + n] - ws[n];
        out[n] = -(logz / (float)ys_lens[n]);
    }
}

extern "C" void kernel_launch(void* const* d_in, const int* in_sizes, int n_in,
                              void* d_out, int out_size, void* d_ws, size_t ws_size,
                              hipStream_t stream)
{
    const float* hs      = (const float*)d_in[0];
    const int*   ys_pad  = (const int*)d_in[2];
    const int*   ys_lens = (const int*)d_in[3];
    const float* W       = (const float*)d_in[4];
    const float* bias    = (const float*)d_in[5];
    float* out = (float*)d_out;
    float* ws  = (float*)d_ws;

    dim3 grid(CG / BN, (NB * T_STEPS) / BM);   // (32, 64)
    crf_gemm_kernel<<<grid, 256, 0, stream>>>(hs, W, bias, out);
    crf_fwd_kernel<<<2 * NB, 1024, 0, stream>>>(out + 16, ys_pad, ys_lens, ws);
    crf_loss_kernel<<<1, 64, 0, stream>>>(ws, ys_lens, out);
}

// Round 2
// 319.305 us; speedup vs baseline: 2.5620x; 2.5620x over previous
//
#include <hip/hip_runtime.h>
#include <hip/hip_bf16.h>
#include <math.h>

#define T_STEPS 512
#define NB      16
#define D_IN    512
#define CG      4096
#define CO      5120
#define NSTATES 1024
#define LMAX    252
#define NEGF    (-1e30f)
#define SCORES_SZ 41943040LL   // NB * T_STEPS * CO
#define L2E 1.4426950408889634f
#define LN2 0.6931471805599453f

typedef __attribute__((ext_vector_type(8))) short bf16x8;
typedef __attribute__((ext_vector_type(4))) float f32x4;

__device__ __forceinline__ float tanh5(float x) {
    x = fminf(fmaxf(x, -15.f), 15.f);
    float e = __expf(2.f * x);
    return 5.f * (e - 1.f) / (e + 1.f);
}

// ---------------- fp32 -> bf16 conversion (RNE) ----------------
__global__ __launch_bounds__(256) void cvt_bf16_kernel(const float* __restrict__ src,
                                                       unsigned short* __restrict__ dst,
                                                       int n4) {
    int i = blockIdx.x * 256 + threadIdx.x;
    if (i < n4) {
        float4 v = *(reinterpret_cast<const float4*>(src) + i);
        ushort4 o;
        __hip_bfloat16 h;
        h = __float2bfloat16(v.x); o.x = *reinterpret_cast<unsigned short*>(&h);
        h = __float2bfloat16(v.y); o.y = *reinterpret_cast<unsigned short*>(&h);
        h = __float2bfloat16(v.z); o.z = *reinterpret_cast<unsigned short*>(&h);
        h = __float2bfloat16(v.w); o.w = *reinterpret_cast<unsigned short*>(&h);
        *(reinterpret_cast<ushort4*>(dst) + i) = o;
    }
}

// ---------------- bf16 MFMA GEMM + tanh*5 + blank interleave ----------------
// 128x128 tile, BK=64, 4 waves, global_load_lds w/ source-preswizzled T2 XOR.
__global__ __launch_bounds__(256) void crf_gemm_bf16(
    const unsigned short* __restrict__ A16,   // (8192, 512) bf16 bits
    const unsigned short* __restrict__ W16,   // (4096, 512) bf16 bits
    const float* __restrict__ bias,
    float* __restrict__ out)
{
    __shared__ unsigned short As[128 * 64];
    __shared__ unsigned short Bs[128 * 64];
    const int tid  = threadIdx.x;
    const int lane = tid & 63;
    const int wv   = __builtin_amdgcn_readfirstlane(tid >> 6);
    const int wr   = wv >> 1, wc = wv & 1;
    const int m0   = blockIdx.y * 128;
    const int n0   = blockIdx.x * 128;
    const int wbase = tid & 192;            // wave * 64

    f32x4 acc[4][4];
    #pragma unroll
    for (int i = 0; i < 4; ++i)
        #pragma unroll
        for (int j = 0; j < 4; ++j) acc[i][j] = (f32x4){0.f, 0.f, 0.f, 0.f};

    const int l15 = lane & 15, lj = lane >> 4, l7 = lane & 7;

    for (int k0 = 0; k0 < D_IN; k0 += 64) {
        __syncthreads();
        #pragma unroll
        for (int i = 0; i < 4; ++i) {
            const int c   = i * 256 + tid;
            const int row = c >> 3;
            const int jg  = (c & 7) ^ (row & 7);       // source pre-swizzle
            const unsigned short* ga = A16 + (size_t)(m0 + row) * D_IN + k0 + jg * 8;
            const unsigned short* gb = W16 + (size_t)(n0 + row) * D_IN + k0 + jg * 8;
            unsigned short* la = As + (size_t)(i * 256 + wbase) * 8;
            unsigned short* lb = Bs + (size_t)(i * 256 + wbase) * 8;
            __builtin_amdgcn_global_load_lds((const __attribute__((address_space(1))) void*)ga,
                                             (__attribute__((address_space(3))) void*)la, 16, 0, 0);
            __builtin_amdgcn_global_load_lds((const __attribute__((address_space(1))) void*)gb,
                                             (__attribute__((address_space(3))) void*)lb, 16, 0, 0);
        }
        __syncthreads();
        #pragma unroll
        for (int ks = 0; ks < 2; ++ks) {
            bf16x8 af[4], bb[4];
            #pragma unroll
            for (int mi = 0; mi < 4; ++mi) {
                const int row = wr * 64 + mi * 16 + l15;
                const int jsw = (ks * 4 + lj) ^ l7;     // read-side swizzle
                af[mi] = *reinterpret_cast<const bf16x8*>(&As[row * 64 + jsw * 8]);
            }
            #pragma unroll
            for (int ni = 0; ni < 4; ++ni) {
                const int row = wc * 64 + ni * 16 + l15;
                const int jsw = (ks * 4 + lj) ^ l7;
                bb[ni] = *reinterpret_cast<const bf16x8*>(&Bs[row * 64 + jsw * 8]);
            }
            #pragma unroll
            for (int mi = 0; mi < 4; ++mi)
                #pragma unroll
                for (int ni = 0; ni < 4; ++ni)
                    acc[mi][ni] = __builtin_amdgcn_mfma_f32_16x16x32_bf16(
                        af[mi], bb[ni], acc[mi][ni], 0, 0, 0);
        }
    }

    // epilogue: C/D layout col = lane&15, row = (lane>>4)*4 + reg  [m89/m91 verified]
    float bv[4];
    #pragma unroll
    for (int ni = 0; ni < 4; ++ni) bv[ni] = bias[n0 + wc * 64 + ni * 16 + l15];

    #pragma unroll
    for (int mi = 0; mi < 4; ++mi) {
        #pragma unroll
        for (int r = 0; r < 4; ++r) {
            const int m = m0 + wr * 64 + mi * 16 + lj * 4 + r;
            float* r1 = out + 16 + (size_t)m * CO;
            #pragma unroll
            for (int ni = 0; ni < 4; ++ni) {
                const int n = n0 + wc * 64 + ni * 16 + l15;
                const float v = tanh5(acc[mi][ni][r] + bv[ni]);
                const int ch = (n >> 2) * 5 + (n & 3) + 1;
                r1[ch] = v;
                r1[ch + SCORES_SZ] = v;
                if ((l15 & 3) == 0) {
                    r1[ch - 1] = 2.0f;
                    r1[ch - 1 + SCORES_SZ] = 2.0f;
                }
            }
        }
    }
}

// ---------------- fp32 fallback GEMM (round-1, known-good) ----------------
#define BM 128
#define BN 128
#define BK 16
__global__ __launch_bounds__(256) void crf_gemm_f32(
    const float* __restrict__ A, const float* __restrict__ W,
    const float* __restrict__ bias, float* __restrict__ out)
{
    __shared__ float As[BK][BM + 4];
    __shared__ float Bs[BK][BN + 4];
    const int tid = threadIdx.x;
    const int tx = tid & 15, ty = tid >> 4;
    const int m0 = blockIdx.y * BM;
    const int n0 = blockIdx.x * BN;
    float acc[8][8];
    #pragma unroll
    for (int i = 0; i < 8; ++i)
        #pragma unroll
        for (int j = 0; j < 8; ++j) acc[i][j] = 0.f;
    const int lrow = tid >> 2;
    const int lk   = (tid & 3) << 2;
    for (int k0 = 0; k0 < D_IN; k0 += BK) {
        #pragma unroll
        for (int h = 0; h < 2; ++h) {
            const int row = lrow + h * 64;
            float4 av = *(const float4*)(A + (size_t)(m0 + row) * D_IN + k0 + lk);
            As[lk + 0][row] = av.x; As[lk + 1][row] = av.y;
            As[lk + 2][row] = av.z; As[lk + 3][row] = av.w;
            float4 wv = *(const float4*)(W + (size_t)(n0 + row) * D_IN + k0 + lk);
            Bs[lk + 0][row] = wv.x; Bs[lk + 1][row] = wv.y;
            Bs[lk + 2][row] = wv.z; Bs[lk + 3][row] = wv.w;
        }
        __syncthreads();
        #pragma unroll
        for (int kk = 0; kk < BK; ++kk) {
            float a[8], bb[8];
            *(float4*)&a[0]  = *(const float4*)&As[kk][ty * 8];
            *(float4*)&a[4]  = *(const float4*)&As[kk][ty * 8 + 4];
            *(float4*)&bb[0] = *(const float4*)&Bs[kk][tx * 8];
            *(float4*)&bb[4] = *(const float4*)&Bs[kk][tx * 8 + 4];
            #pragma unroll
            for (int i = 0; i < 8; ++i)
                #pragma unroll
                for (int j = 0; j < 8; ++j)
                    acc[i][j] = fmaf(a[i], bb[j], acc[i][j]);
        }
        __syncthreads();
    }
    float bv[8];
    #pragma unroll
    for (int j = 0; j < 8; ++j) bv[j] = bias[n0 + tx * 8 + j];
    #pragma unroll
    for (int i = 0; i < 8; ++i) {
        const int m = m0 + ty * 8 + i;
        float* r1 = out + 16 + (size_t)m * CO;
        float* r2 = r1 + SCORES_SZ;
        #pragma unroll
        for (int jg = 0; jg < 2; ++jg) {
            const int c0 = n0 + tx * 8 + jg * 4;
            const int ch = (c0 >> 2) * 5;
            r1[ch] = 2.0f; r2[ch] = 2.0f;
            #pragma unroll
            for (int j = 0; j < 4; ++j) {
                float v = tanh5(acc[i][jg * 4 + j] + bv[jg * 4 + j]);
                r1[ch + 1 + j] = v;
                r2[ch + 1 + j] = v;
            }
        }
    }
}

// ---------------- CRF full-forward + CTC forward (exp2-space, depth-4 prefetch) ----------------
__global__ __launch_bounds__(1024) void crf_fwd_kernel(
    const float* __restrict__ scores,
    const int* __restrict__ ys_pad,
    const int* __restrict__ ys_lens,
    float* __restrict__ ws)
{
    const int blk = blockIdx.x;
    const float STAY = 2.0f * L2E;
    if (blk < NB) {
        const int n = blk;
        const int s = threadIdx.x;
        __shared__ float buf[2][NSTATES];
        __shared__ float red[NSTATES];
        float alpha = 0.f;                       // log2-space
        buf[0][s] = 0.f;
        const int j0 = s >> 2;
        const float* rowp = scores + (size_t)(n * T_STEPS) * CO + 5 * s + 1;
        float pm[4][4];
        #pragma unroll
        for (int u = 0; u < 4; ++u) {
            const float* r = rowp + (size_t)u * CO;
            pm[u][0] = r[0]; pm[u][1] = r[1]; pm[u][2] = r[2]; pm[u][3] = r[3];
        }
        __syncthreads();
        int cur = 0;
        for (int t = 0; t < T_STEPS; t += 4) {
            #pragma unroll
            for (int u = 0; u < 4; ++u) {
                const float m1 = pm[u][0], m2 = pm[u][1], m3 = pm[u][2], m4 = pm[u][3];
                int tp = t + u + 4; if (tp > T_STEPS - 1) tp = T_STEPS - 1;
                const float* r = rowp + (size_t)tp * CO;
                pm[u][0] = r[0]; pm[u][1] = r[1]; pm[u][2] = r[2]; pm[u][3] = r[3];
                const float b1 = buf[cur][j0];
                const float b2 = buf[cur][j0 + 256];
                const float b3 = buf[cur][j0 + 512];
                const float b4 = buf[cur][j0 + 768];
                const float a0 = alpha + STAY;
                const float a1 = fmaf(m1, L2E, b1);
                const float a2 = fmaf(m2, L2E, b2);
                const float a3 = fmaf(m3, L2E, b3);
                const float a4 = fmaf(m4, L2E, b4);
                const float mx = fmaxf(fmaxf(fmaxf(a0, a1), fmaxf(a2, a3)), a4);
                const float sum = __builtin_amdgcn_exp2f(a0 - mx) + __builtin_amdgcn_exp2f(a1 - mx)
                                + __builtin_amdgcn_exp2f(a2 - mx) + __builtin_amdgcn_exp2f(a3 - mx)
                                + __builtin_amdgcn_exp2f(a4 - mx);
                alpha = mx + __builtin_amdgcn_logf(sum);
                buf[cur ^ 1][s] = alpha;
                __syncthreads();
                cur ^= 1;
            }
        }
        red[s] = alpha;
        __syncthreads();
        for (int off = 512; off > 0; off >>= 1) {
            if (s < off) red[s] = fmaxf(red[s], red[s + off]);
            __syncthreads();
        }
        const float gmax = red[0];
        __syncthreads();
        red[s] = __builtin_amdgcn_exp2f(alpha - gmax);
        __syncthreads();
        for (int off = 512; off > 0; off >>= 1) {
            if (s < off) red[s] += red[s + off];
            __syncthreads();
        }
        if (s == 0) ws[n] = LN2 * (gmax + __builtin_amdgcn_logf(red[0]));
    } else {
        const int n = blk - NB;
        const int i = threadIdx.x;
        __shared__ float abuf[2][LMAX];
        __shared__ int tcl[256];
        if (i < 256) tcl[i] = max(ys_pad[n * 256 + i] - 1, 0);
        __syncthreads();
        int mch = -1;
        if (i >= 1 && i < LMAX) {
            const int code = tcl[i] * 256 + tcl[i + 1] * 64 + tcl[i + 2] * 16
                           + tcl[i + 3] * 4 + tcl[i + 4];
            mch = code * 5 + tcl[i - 1] + 1;
        }
        float alpha = (i == 0) ? 0.f : NEGF;     // log2-space (NEGF fine either way)
        if (i < LMAX) abuf[0][i] = alpha;
        const float* base = scores + (size_t)(n * T_STEPS) * CO;
        const size_t moff = (mch >= 0) ? (size_t)mch : 0;
        float pg[4];
        #pragma unroll
        for (int u = 0; u < 4; ++u) pg[u] = base[(size_t)u * CO + moff];
        __syncthreads();
        int cur = 0;
        for (int t = 0; t < T_STEPS; t += 4) {
            #pragma unroll
            for (int u = 0; u < 4; ++u) {
                const float g = pg[u];
                int tp = t + u + 4; if (tp > T_STEPS - 1) tp = T_STEPS - 1;
                pg[u] = base[(size_t)tp * CO + moff];
                if (i < LMAX) {
                    const float a_stay = alpha + STAY;
                    const float prev = (i > 0) ? abuf[cur][i - 1] : NEGF;
                    const float a_mv = (i > 0) ? fmaf(g, L2E, prev) : NEGF;
                    const float mx = fmaxf(a_stay, a_mv);
                    const float mn = fminf(a_stay, a_mv);
                    alpha = mx + __builtin_amdgcn_logf(1.f + __builtin_amdgcn_exp2f(mn - mx));
                    abuf[cur ^ 1][i] = alpha;
                }
                __syncthreads();
                cur ^= 1;
            }
        }
        if (i == ys_lens[n] - 5) ws[NB + n] = alpha * LN2;
    }
}

// ---------------- loss = -((un - logZ) / ys_lens) ----------------
__global__ void crf_loss_kernel(const float* __restrict__ ws,
                                const int* __restrict__ ys_lens,
                                float* __restrict__ out)
{
    const int n = threadIdx.x;
    if (n < NB) {
        const float logz = ws[NB + n] - ws[n];
        out[n] = -(logz / (float)ys_lens[n]);
    }
}

extern "C" void kernel_launch(void* const* d_in, const int* in_sizes, int n_in,
                              void* d_out, int out_size, void* d_ws, size_t ws_size,
                              hipStream_t stream)
{
    const float* hs      = (const float*)d_in[0];
    const int*   ys_pad  = (const int*)d_in[2];
    const int*   ys_lens = (const int*)d_in[3];
    const float* W       = (const float*)d_in[4];
    const float* bias    = (const float*)d_in[5];
    float* out = (float*)d_out;
    float* ws  = (float*)d_ws;

    const size_t A_ELEMS = (size_t)8192 * 512;   // 4,194,304
    const size_t W_ELEMS = (size_t)4096 * 512;   // 2,097,152
    const size_t NEED = 256 + (A_ELEMS + W_ELEMS) * 2;

    if (ws_size >= NEED) {
        unsigned short* A16 = (unsigned short*)((char*)d_ws + 256);
        unsigned short* W16 = A16 + A_ELEMS;
        cvt_bf16_kernel<<<(int)(A_ELEMS / 4 / 256), 256, 0, stream>>>(hs, A16, (int)(A_ELEMS / 4));
        cvt_bf16_kernel<<<(int)(W_ELEMS / 4 / 256), 256, 0, stream>>>(W, W16, (int)(W_ELEMS / 4));
        dim3 grid(CG / 128, (NB * T_STEPS) / 128);   // (32, 64)
        crf_gemm_bf16<<<grid, 256, 0, stream>>>(A16, W16, bias, out);
    } else {
        dim3 grid(CG / BN, (NB * T_STEPS) / BM);
        crf_gemm_f32<<<grid, 256, 0, stream>>>(hs, W, bias, out);
    }
    crf_fwd_kernel<<<2 * NB, 1024, 0, stream>>>(out + 16, ys_pad, ys_lens, ws);
    crf_loss_kernel<<<1, 64, 0, stream>>>(ws, ys_lens, out);
}

// Round 3
// 283.992 us; speedup vs baseline: 2.8806x; 1.1243x over previous
//
#include <hip/hip_runtime.h>
#include <hip/hip_bf16.h>
#include <math.h>

#define T_STEPS 512
#define NB      16
#define D_IN    512
#define CG      4096
#define CO      5120
#define NSTATES 1024
#define LMAX    252
#define NEGF    (-1e30f)
#define SCORES_SZ 41943040LL   // NB * T_STEPS * CO
#define L2E 1.4426950408889634f
#define LN2 0.6931471805599453f

typedef __attribute__((ext_vector_type(8))) short bf16x8;
typedef __attribute__((ext_vector_type(4))) float f32x4;

__device__ __forceinline__ float tanh5(float x) {
    x = fminf(fmaxf(x, -15.f), 15.f);
    float e = __expf(2.f * x);
    return 5.f * (e - 1.f) / (e + 1.f);
}
__device__ __forceinline__ unsigned short f2bf(float v) {
    __hip_bfloat16 h = __float2bfloat16(v);
    return *reinterpret_cast<unsigned short*>(&h);
}
__device__ __forceinline__ float bf_lo(unsigned int u) { return __uint_as_float(u << 16); }
__device__ __forceinline__ float bf_hi(unsigned int u) { return __uint_as_float(u & 0xffff0000u); }

// ---------------- fp32 -> bf16 conversion (RNE) ----------------
__global__ __launch_bounds__(256) void cvt_bf16_kernel(const float* __restrict__ src,
                                                       unsigned short* __restrict__ dst,
                                                       int n4) {
    int i = blockIdx.x * 256 + threadIdx.x;
    if (i < n4) {
        float4 v = *(reinterpret_cast<const float4*>(src) + i);
        ushort4 o;
        o.x = f2bf(v.x); o.y = f2bf(v.y); o.z = f2bf(v.z); o.w = f2bf(v.w);
        *(reinterpret_cast<ushort4*>(dst) + i) = o;
    }
}

// ---------------- bf16 MFMA GEMM + tanh*5 + blank interleave (+ optional bf16 compact copy) ----------------
template <bool WS16>
__global__ __launch_bounds__(256) void crf_gemm_bf16(
    const unsigned short* __restrict__ A16,   // (8192, 512) bf16 bits
    const unsigned short* __restrict__ W16,   // (4096, 512) bf16 bits
    const float* __restrict__ bias,
    float* __restrict__ out,
    unsigned short* __restrict__ s16)         // (8192, 4096) compact bf16 scores
{
    __shared__ unsigned short As[128 * 64];
    __shared__ unsigned short Bs[128 * 64];
    const int tid  = threadIdx.x;
    const int lane = tid & 63;
    const int wv   = __builtin_amdgcn_readfirstlane(tid >> 6);
    const int wr   = wv >> 1, wc = wv & 1;
    const int m0   = blockIdx.y * 128;
    const int n0   = blockIdx.x * 128;
    const int wbase = tid & 192;

    f32x4 acc[4][4];
    #pragma unroll
    for (int i = 0; i < 4; ++i)
        #pragma unroll
        for (int j = 0; j < 4; ++j) acc[i][j] = (f32x4){0.f, 0.f, 0.f, 0.f};

    const int l15 = lane & 15, lj = lane >> 4, l7 = lane & 7;

    for (int k0 = 0; k0 < D_IN; k0 += 64) {
        __syncthreads();
        #pragma unroll
        for (int i = 0; i < 4; ++i) {
            const int c   = i * 256 + tid;
            const int row = c >> 3;
            const int jg  = (c & 7) ^ (row & 7);       // source pre-swizzle
            const unsigned short* ga = A16 + (size_t)(m0 + row) * D_IN + k0 + jg * 8;
            const unsigned short* gb = W16 + (size_t)(n0 + row) * D_IN + k0 + jg * 8;
            unsigned short* la = As + (size_t)(i * 256 + wbase) * 8;
            unsigned short* lb = Bs + (size_t)(i * 256 + wbase) * 8;
            __builtin_amdgcn_global_load_lds((const __attribute__((address_space(1))) void*)ga,
                                             (__attribute__((address_space(3))) void*)la, 16, 0, 0);
            __builtin_amdgcn_global_load_lds((const __attribute__((address_space(1))) void*)gb,
                                             (__attribute__((address_space(3))) void*)lb, 16, 0, 0);
        }
        __syncthreads();
        #pragma unroll
        for (int ks = 0; ks < 2; ++ks) {
            bf16x8 af[4], bb[4];
            #pragma unroll
            for (int mi = 0; mi < 4; ++mi) {
                const int row = wr * 64 + mi * 16 + l15;
                const int jsw = (ks * 4 + lj) ^ l7;
                af[mi] = *reinterpret_cast<const bf16x8*>(&As[row * 64 + jsw * 8]);
            }
            #pragma unroll
            for (int ni = 0; ni < 4; ++ni) {
                const int row = wc * 64 + ni * 16 + l15;
                const int jsw = (ks * 4 + lj) ^ l7;
                bb[ni] = *reinterpret_cast<const bf16x8*>(&Bs[row * 64 + jsw * 8]);
            }
            #pragma unroll
            for (int mi = 0; mi < 4; ++mi)
                #pragma unroll
                for (int ni = 0; ni < 4; ++ni)
                    acc[mi][ni] = __builtin_amdgcn_mfma_f32_16x16x32_bf16(
                        af[mi], bb[ni], acc[mi][ni], 0, 0, 0);
        }
    }

    float bv[4];
    #pragma unroll
    for (int ni = 0; ni < 4; ++ni) bv[ni] = bias[n0 + wc * 64 + ni * 16 + l15];

    #pragma unroll
    for (int mi = 0; mi < 4; ++mi) {
        #pragma unroll
        for (int r = 0; r < 4; ++r) {
            const int m = m0 + wr * 64 + mi * 16 + lj * 4 + r;
            float* r1 = out + 16 + (size_t)m * CO;
            #pragma unroll
            for (int ni = 0; ni < 4; ++ni) {
                const int n = n0 + wc * 64 + ni * 16 + l15;
                const float v = tanh5(acc[mi][ni][r] + bv[ni]);
                const int ch = (n >> 2) * 5 + (n & 3) + 1;
                r1[ch] = v;
                r1[ch + SCORES_SZ] = v;
                if ((l15 & 3) == 0) {
                    r1[ch - 1] = 2.0f;
                    r1[ch - 1 + SCORES_SZ] = 2.0f;
                }
                if (WS16) s16[(size_t)m * CG + n] = f2bf(v);
            }
        }
    }
}

// ---------------- fused CRF (blocks 0..15) + CTC (blocks 16..31), bf16 compact scores ----------------
__global__ __launch_bounds__(512) void fwd_bf16_kernel(
    const unsigned short* __restrict__ s16,   // (8192, 4096)
    const int* __restrict__ ys_pad,
    const int* __restrict__ ys_lens,
    float* __restrict__ ws)
{
    const int blk = blockIdx.x;
    const float STAY = 2.0f * L2E;
    if (blk < NB) {
        // ---- CRF logZ: 512 threads, 2 states/thread, log2-space ----
        const int n = blk;
        const int h = threadIdx.x;         // states 2h, 2h+1
        __shared__ float buf[2][NSTATES];
        __shared__ float red[512];
        float al0 = 0.f, al1 = 0.f;
        *(float2*)&buf[0][2 * h] = make_float2(0.f, 0.f);
        const int j0 = h >> 1;
        const unsigned short* base = s16 + (size_t)(n * T_STEPS) * CG + 8 * h;
        uint4 pf[4];
        #pragma unroll
        for (int u = 0; u < 4; ++u)
            pf[u] = *reinterpret_cast<const uint4*>(base + (size_t)u * CG);
        __syncthreads();
        int cur = 0;
        for (int t = 0; t < T_STEPS; t += 4) {
            #pragma unroll
            for (int u = 0; u < 4; ++u) {
                const uint4 cv = pf[u];
                int tp = t + u + 4; if (tp > T_STEPS - 1) tp = T_STEPS - 1;
                pf[u] = *reinterpret_cast<const uint4*>(base + (size_t)tp * CG);
                const float b1 = buf[cur][j0];
                const float b2 = buf[cur][j0 + 256];
                const float b3 = buf[cur][j0 + 512];
                const float b4 = buf[cur][j0 + 768];
                // state 2h
                {
                    const float a0 = al0 + STAY;
                    const float a1 = fmaf(bf_lo(cv.x), L2E, b1);
                    const float a2 = fmaf(bf_hi(cv.x), L2E, b2);
                    const float a3 = fmaf(bf_lo(cv.y), L2E, b3);
                    const float a4 = fmaf(bf_hi(cv.y), L2E, b4);
                    const float mx = fmaxf(fmaxf(fmaxf(a0, a1), fmaxf(a2, a3)), a4);
                    const float sum = __builtin_amdgcn_exp2f(a0 - mx) + __builtin_amdgcn_exp2f(a1 - mx)
                                    + __builtin_amdgcn_exp2f(a2 - mx) + __builtin_amdgcn_exp2f(a3 - mx)
                                    + __builtin_amdgcn_exp2f(a4 - mx);
                    al0 = mx + __builtin_amdgcn_logf(sum);
                }
                // state 2h+1
                {
                    const float a0 = al1 + STAY;
                    const float a1 = fmaf(bf_lo(cv.z), L2E, b1);
                    const float a2 = fmaf(bf_hi(cv.z), L2E, b2);
                    const float a3 = fmaf(bf_lo(cv.w), L2E, b3);
                    const float a4 = fmaf(bf_hi(cv.w), L2E, b4);
                    const float mx = fmaxf(fmaxf(fmaxf(a0, a1), fmaxf(a2, a3)), a4);
                    const float sum = __builtin_amdgcn_exp2f(a0 - mx) + __builtin_amdgcn_exp2f(a1 - mx)
                                    + __builtin_amdgcn_exp2f(a2 - mx) + __builtin_amdgcn_exp2f(a3 - mx)
                                    + __builtin_amdgcn_exp2f(a4 - mx);
                    al1 = mx + __builtin_amdgcn_logf(sum);
                }
                *(float2*)&buf[cur ^ 1][2 * h] = make_float2(al0, al1);
                __syncthreads();
                cur ^= 1;
            }
        }
        red[h] = fmaxf(al0, al1);
        __syncthreads();
        for (int off = 256; off > 0; off >>= 1) {
            if (h < off) red[h] = fmaxf(red[h], red[h + off]);
            __syncthreads();
        }
        const float gmax = red[0];
        __syncthreads();
        red[h] = __builtin_amdgcn_exp2f(al0 - gmax) + __builtin_amdgcn_exp2f(al1 - gmax);
        __syncthreads();
        for (int off = 256; off > 0; off >>= 1) {
            if (h < off) red[h] += red[h + off];
            __syncthreads();
        }
        if (h == 0) ws[n] = LN2 * (gmax + __builtin_amdgcn_logf(red[0]));
    } else {
        // ---- CTC forward: stay = 2.0 constant (blank), move gathered from compact bf16 ----
        const int n = blk - NB;
        const int i = threadIdx.x;
        __shared__ float abuf[2][LMAX];
        __shared__ int tcl[256];
        if (i < 256) tcl[i] = max(ys_pad[n * 256 + i] - 1, 0);
        __syncthreads();
        int mch = -1;
        if (i >= 1 && i < LMAX) {
            const int code = tcl[i] * 256 + tcl[i + 1] * 64 + tcl[i + 2] * 16
                           + tcl[i + 3] * 4 + tcl[i + 4];
            mch = code * 4 + tcl[i - 1];            // compact (no blank) channel
        }
        float alpha = (i == 0) ? 0.f : NEGF;        // log2-space
        if (i < LMAX) abuf[0][i] = alpha;
        const unsigned short* base = s16 + (size_t)(n * T_STEPS) * CG;
        const size_t moff = (mch >= 0) ? (size_t)mch : 0;
        float pg[4];
        #pragma unroll
        for (int u = 0; u < 4; ++u)
            pg[u] = bf_lo((unsigned int)base[(size_t)u * CG + moff]);
        __syncthreads();
        int cur = 0;
        for (int t = 0; t < T_STEPS; t += 4) {
            #pragma unroll
            for (int u = 0; u < 4; ++u) {
                const float g = pg[u];
                int tp = t + u + 4; if (tp > T_STEPS - 1) tp = T_STEPS - 1;
                pg[u] = bf_lo((unsigned int)base[(size_t)tp * CG + moff]);
                if (i < LMAX) {
                    const float a_stay = alpha + STAY;
                    const float prev = (i > 0) ? abuf[cur][i - 1] : NEGF;
                    const float a_mv = (i > 0) ? fmaf(g, L2E, prev) : NEGF;
                    const float mx = fmaxf(a_stay, a_mv);
                    const float mn = fminf(a_stay, a_mv);
                    alpha = mx + __builtin_amdgcn_logf(1.f + __builtin_amdgcn_exp2f(mn - mx));
                    abuf[cur ^ 1][i] = alpha;
                }
                __syncthreads();
                cur ^= 1;
            }
        }
        if (i == ys_lens[n] - 5) ws[NB + n] = alpha * LN2;
    }
}

// ---------------- round-2 fallback: fused fwd on f32 interleaved scores ----------------
__global__ __launch_bounds__(1024) void crf_fwd_kernel(
    const float* __restrict__ scores,
    const int* __restrict__ ys_pad,
    const int* __restrict__ ys_lens,
    float* __restrict__ ws)
{
    const int blk = blockIdx.x;
    const float STAY = 2.0f * L2E;
    if (blk < NB) {
        const int n = blk;
        const int s = threadIdx.x;
        __shared__ float buf[2][NSTATES];
        __shared__ float red[NSTATES];
        float alpha = 0.f;
        buf[0][s] = 0.f;
        const int j0 = s >> 2;
        const float* rowp = scores + (size_t)(n * T_STEPS) * CO + 5 * s + 1;
        float pm[4][4];
        #pragma unroll
        for (int u = 0; u < 4; ++u) {
            const float* r = rowp + (size_t)u * CO;
            pm[u][0] = r[0]; pm[u][1] = r[1]; pm[u][2] = r[2]; pm[u][3] = r[3];
        }
        __syncthreads();
        int cur = 0;
        for (int t = 0; t < T_STEPS; t += 4) {
            #pragma unroll
            for (int u = 0; u < 4; ++u) {
                const float m1 = pm[u][0], m2 = pm[u][1], m3 = pm[u][2], m4 = pm[u][3];
                int tp = t + u + 4; if (tp > T_STEPS - 1) tp = T_STEPS - 1;
                const float* r = rowp + (size_t)tp * CO;
                pm[u][0] = r[0]; pm[u][1] = r[1]; pm[u][2] = r[2]; pm[u][3] = r[3];
                const float b1 = buf[cur][j0];
                const float b2 = buf[cur][j0 + 256];
                const float b3 = buf[cur][j0 + 512];
                const float b4 = buf[cur][j0 + 768];
                const float a0 = alpha + STAY;
                const float a1 = fmaf(m1, L2E, b1);
                const float a2 = fmaf(m2, L2E, b2);
                const float a3 = fmaf(m3, L2E, b3);
                const float a4 = fmaf(m4, L2E, b4);
                const float mx = fmaxf(fmaxf(fmaxf(a0, a1), fmaxf(a2, a3)), a4);
                const float sum = __builtin_amdgcn_exp2f(a0 - mx) + __builtin_amdgcn_exp2f(a1 - mx)
                                + __builtin_amdgcn_exp2f(a2 - mx) + __builtin_amdgcn_exp2f(a3 - mx)
                                + __builtin_amdgcn_exp2f(a4 - mx);
                alpha = mx + __builtin_amdgcn_logf(sum);
                buf[cur ^ 1][s] = alpha;
                __syncthreads();
                cur ^= 1;
            }
        }
        red[s] = alpha;
        __syncthreads();
        for (int off = 512; off > 0; off >>= 1) {
            if (s < off) red[s] = fmaxf(red[s], red[s + off]);
            __syncthreads();
        }
        const float gmax = red[0];
        __syncthreads();
        red[s] = __builtin_amdgcn_exp2f(alpha - gmax);
        __syncthreads();
        for (int off = 512; off > 0; off >>= 1) {
            if (s < off) red[s] += red[s + off];
            __syncthreads();
        }
        if (s == 0) ws[n] = LN2 * (gmax + __builtin_amdgcn_logf(red[0]));
    } else {
        const int n = blk - NB;
        const int i = threadIdx.x;
        __shared__ float abuf[2][LMAX];
        __shared__ int tcl[256];
        if (i < 256) tcl[i] = max(ys_pad[n * 256 + i] - 1, 0);
        __syncthreads();
        int mch = -1;
        if (i >= 1 && i < LMAX) {
            const int code = tcl[i] * 256 + tcl[i + 1] * 64 + tcl[i + 2] * 16
                           + tcl[i + 3] * 4 + tcl[i + 4];
            mch = code * 5 + tcl[i - 1] + 1;
        }
        float alpha = (i == 0) ? 0.f : NEGF;
        if (i < LMAX) abuf[0][i] = alpha;
        const float* base = scores + (size_t)(n * T_STEPS) * CO;
        const size_t moff = (mch >= 0) ? (size_t)mch : 0;
        float pg[4];
        #pragma unroll
        for (int u = 0; u < 4; ++u) pg[u] = base[(size_t)u * CO + moff];
        __syncthreads();
        int cur = 0;
        for (int t = 0; t < T_STEPS; t += 4) {
            #pragma unroll
            for (int u = 0; u < 4; ++u) {
                const float g = pg[u];
                int tp = t + u + 4; if (tp > T_STEPS - 1) tp = T_STEPS - 1;
                pg[u] = base[(size_t)tp * CO + moff];
                if (i < LMAX) {
                    const float a_stay = alpha + STAY;
                    const float prev = (i > 0) ? abuf[cur][i - 1] : NEGF;
                    const float a_mv = (i > 0) ? fmaf(g, L2E, prev) : NEGF;
                    const float mx = fmaxf(a_stay, a_mv);
                    const float mn = fminf(a_stay, a_mv);
                    alpha = mx + __builtin_amdgcn_logf(1.f + __builtin_amdgcn_exp2f(mn - mx));
                    abuf[cur ^ 1][i] = alpha;
                }
                __syncthreads();
                cur ^= 1;
            }
        }
        if (i == ys_lens[n] - 5) ws[NB + n] = alpha * LN2;
    }
}

// ---------------- loss = -((un - logZ) / ys_lens) ----------------
__global__ void crf_loss_kernel(const float* __restrict__ ws,
                                const int* __restrict__ ys_lens,
                                float* __restrict__ out)
{
    const int n = threadIdx.x;
    if (n < NB) {
        const float logz = ws[NB + n] - ws[n];
        out[n] = -(logz / (float)ys_lens[n]);
    }
}

extern "C" void kernel_launch(void* const* d_in, const int* in_sizes, int n_in,
                              void* d_out, int out_size, void* d_ws, size_t ws_size,
                              hipStream_t stream)
{
    const float* hs      = (const float*)d_in[0];
    const int*   ys_pad  = (const int*)d_in[2];
    const int*   ys_lens = (const int*)d_in[3];
    const float* W       = (const float*)d_in[4];
    const float* bias    = (const float*)d_in[5];
    float* out = (float*)d_out;
    float* ws  = (float*)d_ws;

    const size_t A_ELEMS = (size_t)8192 * 512;
    const size_t W_ELEMS = (size_t)4096 * 512;
    const size_t S_ELEMS = (size_t)8192 * 4096;
    const size_t NEED1 = 256 + (A_ELEMS + W_ELEMS) * 2;
    const size_t NEED2 = NEED1 + S_ELEMS * 2;

    unsigned short* A16 = (unsigned short*)((char*)d_ws + 256);
    unsigned short* W16 = A16 + A_ELEMS;
    unsigned short* S16 = W16 + W_ELEMS;

    if (ws_size >= NEED2) {
        cvt_bf16_kernel<<<(int)(A_ELEMS / 4 / 256), 256, 0, stream>>>(hs, A16, (int)(A_ELEMS / 4));
        cvt_bf16_kernel<<<(int)(W_ELEMS / 4 / 256), 256, 0, stream>>>(W, W16, (int)(W_ELEMS / 4));
        dim3 grid(CG / 128, (NB * T_STEPS) / 128);
        crf_gemm_bf16<true><<<grid, 256, 0, stream>>>(A16, W16, bias, out, S16);
        fwd_bf16_kernel<<<2 * NB, 512, 0, stream>>>(S16, ys_pad, ys_lens, ws);
    } else {
        cvt_bf16_kernel<<<(int)(A_ELEMS / 4 / 256), 256, 0, stream>>>(hs, A16, (int)(A_ELEMS / 4));
        cvt_bf16_kernel<<<(int)(W_ELEMS / 4 / 256), 256, 0, stream>>>(W, W16, (int)(W_ELEMS / 4));
        dim3 grid(CG / 128, (NB * T_STEPS) / 128);
        crf_gemm_bf16<false><<<grid, 256, 0, stream>>>(A16, W16, bias, out, nullptr);
        crf_fwd_kernel<<<2 * NB, 1024, 0, stream>>>(out + 16, ys_pad, ys_lens, ws);
    }
    crf_loss_kernel<<<1, 64, 0, stream>>>(ws, ys_lens, out);
}

// Round 4
// 240.157 us; speedup vs baseline: 3.4063x; 1.1825x over previous
//
#include <hip/hip_runtime.h>
#include <hip/hip_bf16.h>
#include <hip/hip_fp16.h>
#include <math.h>

#define T_STEPS 512
#define NB      16
#define D_IN    512
#define CG      4096
#define CO      5120
#define NSTATES 1024
#define LMAX    252
#define NEGF    (-1e30f)
#define SCORES_SZ 41943040LL   // NB * T_STEPS * CO
#define L2E 1.4426950408889634f
#define LN2 0.6931471805599453f

typedef __attribute__((ext_vector_type(8))) short bf16x8;
typedef __attribute__((ext_vector_type(4))) float f32x4;

__device__ __forceinline__ float tanh5(float x) {
    x = fminf(fmaxf(x, -15.f), 15.f);
    float e = __expf(2.f * x);
    return 5.f * (e - 1.f) / (e + 1.f);
}
__device__ __forceinline__ unsigned short f2bf(float v) {
    __hip_bfloat16 h = __float2bfloat16(v);
    return *reinterpret_cast<unsigned short*>(&h);
}
__device__ __forceinline__ float h2f(unsigned short s) {
    union { unsigned short u; _Float16 h; } c; c.u = s;
    return (float)c.h;
}
__device__ __forceinline__ unsigned short f2h(float v) {
    union { unsigned short u; _Float16 h; } c; c.h = (_Float16)v;
    return c.u;
}

// ---------------- fp32 -> bf16 conversion (RNE) ----------------
__global__ __launch_bounds__(256) void cvt_bf16_kernel(const float* __restrict__ src,
                                                       unsigned short* __restrict__ dst,
                                                       int n4) {
    int i = blockIdx.x * 256 + threadIdx.x;
    if (i < n4) {
        float4 v = *(reinterpret_cast<const float4*>(src) + i);
        ushort4 o;
        o.x = f2bf(v.x); o.y = f2bf(v.y); o.z = f2bf(v.z); o.w = f2bf(v.w);
        *(reinterpret_cast<ushort4*>(dst) + i) = o;
    }
}

// ---------------- bf16 MFMA GEMM + tanh*5 + blank interleave (+ exp-score f16 copy) ----------------
template <bool WSE>
__global__ __launch_bounds__(256) void crf_gemm_bf16(
    const unsigned short* __restrict__ A16,   // (8192, 512) bf16 bits
    const unsigned short* __restrict__ W16,   // (4096, 512) bf16 bits
    const float* __restrict__ bias,
    float* __restrict__ out,
    unsigned short* __restrict__ e16)         // (8192, 4096) f16 exp(score)
{
    __shared__ unsigned short As[128 * 64];
    __shared__ unsigned short Bs[128 * 64];
    const int tid  = threadIdx.x;
    const int lane = tid & 63;
    const int wv   = __builtin_amdgcn_readfirstlane(tid >> 6);
    const int wr   = wv >> 1, wc = wv & 1;
    const int m0   = blockIdx.y * 128;
    const int n0   = blockIdx.x * 128;
    const int wbase = tid & 192;

    f32x4 acc[4][4];
    #pragma unroll
    for (int i = 0; i < 4; ++i)
        #pragma unroll
        for (int j = 0; j < 4; ++j) acc[i][j] = (f32x4){0.f, 0.f, 0.f, 0.f};

    const int l15 = lane & 15, lj = lane >> 4, l7 = lane & 7;

    for (int k0 = 0; k0 < D_IN; k0 += 64) {
        __syncthreads();
        #pragma unroll
        for (int i = 0; i < 4; ++i) {
            const int c   = i * 256 + tid;
            const int row = c >> 3;
            const int jg  = (c & 7) ^ (row & 7);       // source pre-swizzle
            const unsigned short* ga = A16 + (size_t)(m0 + row) * D_IN + k0 + jg * 8;
            const unsigned short* gb = W16 + (size_t)(n0 + row) * D_IN + k0 + jg * 8;
            unsigned short* la = As + (size_t)(i * 256 + wbase) * 8;
            unsigned short* lb = Bs + (size_t)(i * 256 + wbase) * 8;
            __builtin_amdgcn_global_load_lds((const __attribute__((address_space(1))) void*)ga,
                                             (__attribute__((address_space(3))) void*)la, 16, 0, 0);
            __builtin_amdgcn_global_load_lds((const __attribute__((address_space(1))) void*)gb,
                                             (__attribute__((address_space(3))) void*)lb, 16, 0, 0);
        }
        __syncthreads();
        #pragma unroll
        for (int ks = 0; ks < 2; ++ks) {
            bf16x8 af[4], bb[4];
            #pragma unroll
            for (int mi = 0; mi < 4; ++mi) {
                const int row = wr * 64 + mi * 16 + l15;
                const int jsw = (ks * 4 + lj) ^ l7;
                af[mi] = *reinterpret_cast<const bf16x8*>(&As[row * 64 + jsw * 8]);
            }
            #pragma unroll
            for (int ni = 0; ni < 4; ++ni) {
                const int row = wc * 64 + ni * 16 + l15;
                const int jsw = (ks * 4 + lj) ^ l7;
                bb[ni] = *reinterpret_cast<const bf16x8*>(&Bs[row * 64 + jsw * 8]);
            }
            #pragma unroll
            for (int mi = 0; mi < 4; ++mi)
                #pragma unroll
                for (int ni = 0; ni < 4; ++ni)
                    acc[mi][ni] = __builtin_amdgcn_mfma_f32_16x16x32_bf16(
                        af[mi], bb[ni], acc[mi][ni], 0, 0, 0);
        }
    }

    float bv[4];
    #pragma unroll
    for (int ni = 0; ni < 4; ++ni) bv[ni] = bias[n0 + wc * 64 + ni * 16 + l15];

    #pragma unroll
    for (int mi = 0; mi < 4; ++mi) {
        #pragma unroll
        for (int r = 0; r < 4; ++r) {
            const int m = m0 + wr * 64 + mi * 16 + lj * 4 + r;
            float* r1 = out + 16 + (size_t)m * CO;
            #pragma unroll
            for (int ni = 0; ni < 4; ++ni) {
                const int n = n0 + wc * 64 + ni * 16 + l15;
                const float v = tanh5(acc[mi][ni][r] + bv[ni]);
                const int ch = (n >> 2) * 5 + (n & 3) + 1;
                r1[ch] = v;
                r1[ch + SCORES_SZ] = v;
                if ((l15 & 3) == 0) {
                    r1[ch - 1] = 2.0f;
                    r1[ch - 1 + SCORES_SZ] = 2.0f;
                }
                if (WSE) e16[(size_t)m * CG + n] = f2h(__expf(v));
            }
        }
    }
}

__device__ __forceinline__ void cvt8(uint4 u, float* g) {
    g[0] = h2f((unsigned short)(u.x & 0xffff)); g[1] = h2f((unsigned short)(u.x >> 16));
    g[2] = h2f((unsigned short)(u.y & 0xffff)); g[3] = h2f((unsigned short)(u.y >> 16));
    g[4] = h2f((unsigned short)(u.z & 0xffff)); g[5] = h2f((unsigned short)(u.z >> 16));
    g[6] = h2f((unsigned short)(u.w & 0xffff)); g[7] = h2f((unsigned short)(u.w >> 16));
}

// ---------------- prob-domain CRF (blocks 0..15) + log-domain CTC (blocks 16..31) ----------------
__global__ __launch_bounds__(256) void fwd_pd_kernel(
    const unsigned short* __restrict__ e16,   // (8192, 4096) f16 exp(score)
    const int* __restrict__ ys_pad,
    const int* __restrict__ ys_lens,
    float* __restrict__ ws)
{
    const int blk = blockIdx.x;
    if (blk < NB) {
        // ---- CRF logZ in probability domain: 256 threads x 4 states ----
        const int n = blk;
        const int q = threadIdx.x;                 // states 4q..4q+3
        const int lane = q & 63, wvi = q >> 6;
        __shared__ float buf[2][NSTATES];
        __shared__ float red[256];
        __shared__ float wmax4[4];
        const float e2 = 7.38905609893065f;        // exp(2.0) stay factor
        float P0 = 1.f, P1 = 1.f, P2 = 1.f, P3 = 1.f;
        float acc = 0.f;                           // accumulated log2 scale
        *(float4*)&buf[0][4 * q] = make_float4(1.f, 1.f, 1.f, 1.f);
        const unsigned short* base = e16 + (size_t)(n * T_STEPS) * CG + 16 * q;
        uint4 pf[4][2];
        #pragma unroll
        for (int u = 0; u < 4; ++u) {
            pf[u][0] = *reinterpret_cast<const uint4*>(base + (size_t)u * CG);
            pf[u][1] = *reinterpret_cast<const uint4*>(base + (size_t)u * CG + 8);
        }
        __syncthreads();
        int cur = 0;
        for (int t = 0; t < T_STEPS; t += 8) {
            #pragma unroll
            for (int u = 0; u < 8; ++u) {
                float g[16];
                cvt8(pf[u & 3][0], g);
                cvt8(pf[u & 3][1], g + 8);
                int tp = t + u + 4; if (tp > T_STEPS - 1) tp = T_STEPS - 1;
                const unsigned short* rp = base + (size_t)tp * CG;
                pf[u & 3][0] = *reinterpret_cast<const uint4*>(rp);
                pf[u & 3][1] = *reinterpret_cast<const uint4*>(rp + 8);
                const float b0 = buf[cur][q];
                const float b1 = buf[cur][q + 256];
                const float b2 = buf[cur][q + 512];
                const float b3 = buf[cur][q + 768];
                float n0 = fmaf(e2, P0, fmaf(g[0],  b0, g[1]  * b1) + fmaf(g[2],  b2, g[3]  * b3));
                float n1 = fmaf(e2, P1, fmaf(g[4],  b0, g[5]  * b1) + fmaf(g[6],  b2, g[7]  * b3));
                float n2 = fmaf(e2, P2, fmaf(g[8],  b0, g[9]  * b1) + fmaf(g[10], b2, g[11] * b3));
                float n3 = fmaf(e2, P3, fmaf(g[12], b0, g[13] * b1) + fmaf(g[14], b2, g[15] * b3));
                if (u == 1) {
                    // apply power-of-2 renorm from step t's max (1-step stale, safe)
                    const float wm = fmaxf(fmaxf(wmax4[0], wmax4[1]), fmaxf(wmax4[2], wmax4[3]));
                    const int e = (int)((__float_as_uint(wm) >> 23) & 0xff) - 127;
                    const float c = __uint_as_float((unsigned)(127 - e) << 23);
                    n0 *= c; n1 *= c; n2 *= c; n3 *= c;
                    acc += (float)e;
                }
                P0 = n0; P1 = n1; P2 = n2; P3 = n3;
                *(float4*)&buf[cur ^ 1][4 * q] = make_float4(P0, P1, P2, P3);
                if (u == 0) {
                    float lm = fmaxf(fmaxf(P0, P1), fmaxf(P2, P3));
                    #pragma unroll
                    for (int msk = 1; msk < 64; msk <<= 1)
                        lm = fmaxf(lm, __shfl_xor(lm, msk, 64));
                    if (lane == 0) wmax4[wvi] = lm;
                }
                __syncthreads();
                cur ^= 1;
            }
        }
        red[q] = (P0 + P1) + (P2 + P3);
        __syncthreads();
        for (int off = 128; off > 0; off >>= 1) {
            if (q < off) red[q] += red[q + off];
            __syncthreads();
        }
        if (q == 0) ws[n] = LN2 * (acc + __builtin_amdgcn_logf(red[0]));
    } else {
        // ---- CTC forward, log2 domain; move scores = log2(E16 gathered) ----
        const int n = blk - NB;
        const int i = threadIdx.x;
        const float STAY = 2.0f * L2E;
        __shared__ float abuf[2][LMAX];
        __shared__ int tcl[256];
        if (i < 256) tcl[i] = max(ys_pad[n * 256 + i] - 1, 0);
        __syncthreads();
        int mch = -1;
        if (i >= 1 && i < LMAX) {
            const int code = tcl[i] * 256 + tcl[i + 1] * 64 + tcl[i + 2] * 16
                           + tcl[i + 3] * 4 + tcl[i + 4];
            mch = code * 4 + tcl[i - 1];            // compact exp-score channel
        }
        float alpha = (i == 0) ? 0.f : NEGF;        // log2-space
        if (i < LMAX) abuf[0][i] = alpha;
        const unsigned short* base = e16 + (size_t)(n * T_STEPS) * CG;
        const size_t moff = (mch >= 0) ? (size_t)mch : 0;
        float pg[4];
        #pragma unroll
        for (int u = 0; u < 4; ++u) pg[u] = h2f(base[(size_t)u * CG + moff]);
        __syncthreads();
        int cur = 0;
        for (int t = 0; t < T_STEPS; t += 4) {
            #pragma unroll
            for (int u = 0; u < 4; ++u) {
                const float g2 = __builtin_amdgcn_logf(pg[u]);   // log2(exp(m))
                int tp = t + u + 4; if (tp > T_STEPS - 1) tp = T_STEPS - 1;
                pg[u] = h2f(base[(size_t)tp * CG + moff]);
                if (i < LMAX) {
                    const float a_stay = alpha + STAY;
                    const float prev = (i > 0) ? abuf[cur][i - 1] : NEGF;
                    const float a_mv = (i > 0) ? (prev + g2) : NEGF;
                    const float mx = fmaxf(a_stay, a_mv);
                    const float mn = fminf(a_stay, a_mv);
                    alpha = mx + __builtin_amdgcn_logf(1.f + __builtin_amdgcn_exp2f(mn - mx));
                    abuf[cur ^ 1][i] = alpha;
                }
                __syncthreads();
                cur ^= 1;
            }
        }
        if (i == ys_lens[n] - 5) ws[NB + n] = alpha * LN2;
    }
}

// ---------------- fallback: fused fwd on f32 interleaved scores (round-2, known-good) ----------------
__global__ __launch_bounds__(1024) void crf_fwd_kernel(
    const float* __restrict__ scores,
    const int* __restrict__ ys_pad,
    const int* __restrict__ ys_lens,
    float* __restrict__ ws)
{
    const int blk = blockIdx.x;
    const float STAY = 2.0f * L2E;
    if (blk < NB) {
        const int n = blk;
        const int s = threadIdx.x;
        __shared__ float buf[2][NSTATES];
        __shared__ float red[NSTATES];
        float alpha = 0.f;
        buf[0][s] = 0.f;
        const int j0 = s >> 2;
        const float* rowp = scores + (size_t)(n * T_STEPS) * CO + 5 * s + 1;
        float pm[4][4];
        #pragma unroll
        for (int u = 0; u < 4; ++u) {
            const float* r = rowp + (size_t)u * CO;
            pm[u][0] = r[0]; pm[u][1] = r[1]; pm[u][2] = r[2]; pm[u][3] = r[3];
        }
        __syncthreads();
        int cur = 0;
        for (int t = 0; t < T_STEPS; t += 4) {
            #pragma unroll
            for (int u = 0; u < 4; ++u) {
                const float m1 = pm[u][0], m2 = pm[u][1], m3 = pm[u][2], m4 = pm[u][3];
                int tp = t + u + 4; if (tp > T_STEPS - 1) tp = T_STEPS - 1;
                const float* r = rowp + (size_t)tp * CO;
                pm[u][0] = r[0]; pm[u][1] = r[1]; pm[u][2] = r[2]; pm[u][3] = r[3];
                const float b1 = buf[cur][j0];
                const float b2 = buf[cur][j0 + 256];
                const float b3 = buf[cur][j0 + 512];
                const float b4 = buf[cur][j0 + 768];
                const float a0 = alpha + STAY;
                const float a1 = fmaf(m1, L2E, b1);
                const float a2 = fmaf(m2, L2E, b2);
                const float a3 = fmaf(m3, L2E, b3);
                const float a4 = fmaf(m4, L2E, b4);
                const float mx = fmaxf(fmaxf(fmaxf(a0, a1), fmaxf(a2, a3)), a4);
                const float sum = __builtin_amdgcn_exp2f(a0 - mx) + __builtin_amdgcn_exp2f(a1 - mx)
                                + __builtin_amdgcn_exp2f(a2 - mx) + __builtin_amdgcn_exp2f(a3 - mx)
                                + __builtin_amdgcn_exp2f(a4 - mx);
                alpha = mx + __builtin_amdgcn_logf(sum);
                buf[cur ^ 1][s] = alpha;
                __syncthreads();
                cur ^= 1;
            }
        }
        red[s] = alpha;
        __syncthreads();
        for (int off = 512; off > 0; off >>= 1) {
            if (s < off) red[s] = fmaxf(red[s], red[s + off]);
            __syncthreads();
        }
        const float gmax = red[0];
        __syncthreads();
        red[s] = __builtin_amdgcn_exp2f(alpha - gmax);
        __syncthreads();
        for (int off = 512; off > 0; off >>= 1) {
            if (s < off) red[s] += red[s + off];
            __syncthreads();
        }
        if (s == 0) ws[n] = LN2 * (gmax + __builtin_amdgcn_logf(red[0]));
    } else {
        const int n = blk - NB;
        const int i = threadIdx.x;
        __shared__ float abuf[2][LMAX];
        __shared__ int tcl[256];
        if (i < 256) tcl[i] = max(ys_pad[n * 256 + i] - 1, 0);
        __syncthreads();
        int mch = -1;
        if (i >= 1 && i < LMAX) {
            const int code = tcl[i] * 256 + tcl[i + 1] * 64 + tcl[i + 2] * 16
                           + tcl[i + 3] * 4 + tcl[i + 4];
            mch = code * 5 + tcl[i - 1] + 1;
        }
        float alpha = (i == 0) ? 0.f : NEGF;
        if (i < LMAX) abuf[0][i] = alpha;
        const float* base = scores + (size_t)(n * T_STEPS) * CO;
        const size_t moff = (mch >= 0) ? (size_t)mch : 0;
        float pg[4];
        #pragma unroll
        for (int u = 0; u < 4; ++u) pg[u] = base[(size_t)u * CO + moff];
        __syncthreads();
        int cur = 0;
        for (int t = 0; t < T_STEPS; t += 4) {
            #pragma unroll
            for (int u = 0; u < 4; ++u) {
                const float g = pg[u];
                int tp = t + u + 4; if (tp > T_STEPS - 1) tp = T_STEPS - 1;
                pg[u] = base[(size_t)tp * CO + moff];
                if (i < LMAX) {
                    const float a_stay = alpha + STAY;
                    const float prev = (i > 0) ? abuf[cur][i - 1] : NEGF;
                    const float a_mv = (i > 0) ? fmaf(g, L2E, prev) : NEGF;
                    const float mx = fmaxf(a_stay, a_mv);
                    const float mn = fminf(a_stay, a_mv);
                    alpha = mx + __builtin_amdgcn_logf(1.f + __builtin_amdgcn_exp2f(mn - mx));
                    abuf[cur ^ 1][i] = alpha;
                }
                __syncthreads();
                cur ^= 1;
            }
        }
        if (i == ys_lens[n] - 5) ws[NB + n] = alpha * LN2;
    }
}

// ---------------- loss = -((un - logZ) / ys_lens) ----------------
__global__ void crf_loss_kernel(const float* __restrict__ ws,
                                const int* __restrict__ ys_lens,
                                float* __restrict__ out)
{
    const int n = threadIdx.x;
    if (n < NB) {
        const float logz = ws[NB + n] - ws[n];
        out[n] = -(logz / (float)ys_lens[n]);
    }
}

extern "C" void kernel_launch(void* const* d_in, const int* in_sizes, int n_in,
                              void* d_out, int out_size, void* d_ws, size_t ws_size,
                              hipStream_t stream)
{
    const float* hs      = (const float*)d_in[0];
    const int*   ys_pad  = (const int*)d_in[2];
    const int*   ys_lens = (const int*)d_in[3];
    const float* W       = (const float*)d_in[4];
    const float* bias    = (const float*)d_in[5];
    float* out = (float*)d_out;
    float* ws  = (float*)d_ws;

    const size_t A_ELEMS = (size_t)8192 * 512;
    const size_t W_ELEMS = (size_t)4096 * 512;
    const size_t S_ELEMS = (size_t)8192 * 4096;
    const size_t NEED2 = 256 + (A_ELEMS + W_ELEMS) * 2 + S_ELEMS * 2;

    unsigned short* A16 = (unsigned short*)((char*)d_ws + 256);
    unsigned short* W16 = A16 + A_ELEMS;
    unsigned short* E16 = W16 + W_ELEMS;

    cvt_bf16_kernel<<<(int)(A_ELEMS / 4 / 256), 256, 0, stream>>>(hs, A16, (int)(A_ELEMS / 4));
    cvt_bf16_kernel<<<(int)(W_ELEMS / 4 / 256), 256, 0, stream>>>(W, W16, (int)(W_ELEMS / 4));
    dim3 grid(CG / 128, (NB * T_STEPS) / 128);

    if (ws_size >= NEED2) {
        crf_gemm_bf16<true><<<grid, 256, 0, stream>>>(A16, W16, bias, out, E16);
        fwd_pd_kernel<<<2 * NB, 256, 0, stream>>>(E16, ys_pad, ys_lens, ws);
    } else {
        crf_gemm_bf16<false><<<grid, 256, 0, stream>>>(A16, W16, bias, out, nullptr);
        crf_fwd_kernel<<<2 * NB, 1024, 0, stream>>>(out + 16, ys_pad, ys_lens, ws);
    }
    crf_loss_kernel<<<1, 64, 0, stream>>>(ws, ys_lens, out);
}